// Round 12
// baseline (142.653 us; speedup 1.0000x reference)
//
#include <hip/hip_runtime.h>
#include <math.h>

// KoLeo loss: B=8, T=4096, D=256 fp32 input.
// Phase 1: convert x -> fp8 e4m3 (HW v_cvt_pk_fp8_f32) in ws
// Phase 2: per-batch Gram X·X^T via fp8 MFMA (argmax only needs ranking);
//          A (256 rows, fp8) register-resident at HALF the bf16 VGPR cost ->
//          Ar=64 rows/wave AND 2 blocks/CU simultaneously (bf16 couldn't);
//          B staged via global_load_lds (swizzled, 2x16KB dbuf);
//          streaming per-row argmax merged across s-quarters via atomicMax keys.
// Phase 3: exact fp32 distances to argmax neighbor, loss = -mean(log(dist+eps)).

#define Bq 8
#define Tq 4096
#define Dq 256
#define SBLK 64              // s-columns staged per tile
#define NST 16               // tiles per s-quarter: 1024 / 64
#define S_QUART 1024
#define TILEB (SBLK * 256)   // 16 KB (fp8: 256 B per row)

typedef __attribute__((ext_vector_type(4))) float f32x4;
typedef unsigned int u32;
typedef unsigned long long u64;

__device__ __forceinline__ void gload_lds16(const void* g, void* l) {
    typedef __attribute__((address_space(1))) const unsigned int gu32;
    typedef __attribute__((address_space(3))) unsigned int lu32;
    __builtin_amdgcn_global_load_lds((gu32*)g, (lu32*)l, 16, 0, 0);
}

__device__ __forceinline__ u64 packkey(float v, int ix) {
    const u32 u = __float_as_uint(v);
    const u32 o = (u & 0x80000000u) ? ~u : (u | 0x80000000u);   // orderable fp32
    return ((u64)o << 32) | (u32)(~ix);                         // ties: low idx wins
}

// ---------------- Phase 1: fp32 -> fp8 e4m3 (8 floats/thread) ----------------
__global__ void cvt_kernel(const float* __restrict__ x, uint2* __restrict__ xq) {
    const int i = blockIdx.x * blockDim.x + threadIdx.x;   // 0 .. 1M-1
    const float4* in = (const float4*)x;
    float4 v0 = in[2 * i], v1 = in[2 * i + 1];
    u32 a = 0, b = 0, c = 0, d = 0;
    asm volatile("v_cvt_pk_fp8_f32 %0, %1, %2" : "+v"(a) : "v"(v0.x), "v"(v0.y));
    asm volatile("v_cvt_pk_fp8_f32 %0, %1, %2" : "+v"(b) : "v"(v0.z), "v"(v0.w));
    asm volatile("v_cvt_pk_fp8_f32 %0, %1, %2" : "+v"(c) : "v"(v1.x), "v"(v1.y));
    asm volatile("v_cvt_pk_fp8_f32 %0, %1, %2" : "+v"(d) : "v"(v1.z), "v"(v1.w));
    uint2 o;
    o.x = (a & 0xffffu) | (b << 16);
    o.y = (c & 0xffffu) | (d << 16);
    xq[i] = o;
}

// ---------------- Phase 2: fp8 Gram + streaming argmax ----------------
// Grid: 512 blocks = 8 batches x 16 row-tiles(256 rows) x 4 s-quarters(1024 cols).
//   batch = bid & 7 -> same-batch blocks share an XCD L2 (fp8 panel = 1 MB).
// Block: 512 threads = 8 waves as 4M x 2N. Wave: 64 rows (mi=4); per tile the
//   wave's 32 cols are done as 2 passes of 16 (ni=1, acc[4] reused -> 16 VGPR).
// mfma_f32_16x16x32_fp8_fp8: A/B frag = 8 fp8/lane (1 x i64), layout the exact
//   analog of the verified bf16 16x16x32 (lane&15 = row/col, k = (lane>>4)*8+j);
//   C/D layout dtype-independent: col=lane&15, row=(lane>>4)*4+reg.
// afrag[8][4] = 64 VGPR (HALF of bf16) -> fits 2 blocks/CU at 4 waves/SIMD
//   while keeping Ar=64 (LDS traffic 537 MB, 4x less than R11, 2x less than R10).
// LDS: 2 x 16 KB dbuf; swizzle XOR ((s&15)<<4) on 256 B rows (16B-granular ->
//   staging-compatible; b64 reads land 2 lanes/bank = free).
__global__ __launch_bounds__(512, 4)
void argmax_kernel(const unsigned char* __restrict__ xq, u64* __restrict__ keys) {
    const int bid   = blockIdx.x;
    const int batch = bid & 7;
    const int rt    = (bid >> 3) & 15;     // row-tile 0..15 (256 rows each)
    const int sq    = bid >> 7;            // s-quarter 0..3
    const int tid   = threadIdx.x;
    const int lane  = tid & 63;
    const int wave  = tid >> 6;            // 0..7
    const int waveM = wave >> 1;           // 0..3
    const int waveN = wave & 1;            // 0..1
    const int lrow  = lane & 15;           // A-row / B-col / C-col
    const int lk    = lane >> 4;           // k-group / C row-group

    const unsigned char* xB = xq + (size_t)batch * Tq * Dq;   // fp8, row = 256 B
    const int rowBase = rt * 256 + waveM * 64;                // wave's 64 rows
    const int sQuartBase = sq * S_QUART;
    const int sW = waveN * 32;                                // wave's 32-col slice

    __shared__ char smem[2 * TILEB];                          // 32 KB double buffer

    // ---- A fragments: afrag[kk][mi] = 8x4 x i64 = 64 VGPR ----
    long afrag[8][4];
#pragma unroll
    for (int mi = 0; mi < 4; ++mi) {
        const unsigned char* rp = xB + (size_t)(rowBase + mi * 16 + lrow) * Dq + lk * 8;
#pragma unroll
        for (int kk = 0; kk < 8; ++kk)
            afrag[kk][mi] = *(const long*)(rp + kk * 32);
    }

    // ---- staging source offsets (2 x 16B per thread per 16 KB tile) ----
    // LDS linear slot ls holds global byte (q ^ ((s&15)<<4)) of row s=ls>>8.
    int g_off[2];
#pragma unroll
    for (int it = 0; it < 2; ++it) {
        const int ls = it * 8192 + tid * 16;
        const int s_local = ls >> 8;
        const int q = ls & 255;
        g_off[it] = s_local * 256 + (q ^ ((s_local & 15) << 4));
    }
    // ---- ds-read offsets (pass 0); pass 1 = +16 rows = +4096, swizzle
    //      invariant because (s+16)&15 == s&15 ----
    int dsoff[8];
    {
        const int s_local = sW + lrow;
#pragma unroll
        for (int kk = 0; kk < 8; ++kk)
            dsoff[kk] = s_local * 256 + ((kk * 32 + lk * 8) ^ ((s_local & 15) << 4));
    }

    auto STAGE = [&](int st, int buf) {
        const unsigned char* gsrc = xB + (size_t)(sQuartBase + st * SBLK) * 256;
        char* lbase = smem + buf * TILEB;
#pragma unroll
        for (int it = 0; it < 2; ++it)
            gload_lds16(gsrc + g_off[it], lbase + it * 8192 + tid * 16);
    };

    float best[4][4];   // [mi][j]
    int   bidxv[4][4];
#pragma unroll
    for (int mi = 0; mi < 4; ++mi)
#pragma unroll
        for (int j = 0; j < 4; ++j) { best[mi][j] = -1e30f; bidxv[mi][j] = 0; }

    STAGE(0, 0);
    asm volatile("s_waitcnt vmcnt(0)");
    __syncthreads();

    for (int st = 0; st < NST; ++st) {
        const int buf = st & 1;
        if (st + 1 < NST) STAGE(st + 1, buf ^ 1);

        const char* lbase = smem + buf * TILEB;
        const int S0 = sQuartBase + st * SBLK;

#pragma unroll
        for (int p = 0; p < 2; ++p) {          // two 16-col passes per wave
            f32x4 acc[4];
#pragma unroll
            for (int mi = 0; mi < 4; ++mi)
                acc[mi] = (f32x4){0.f, 0.f, 0.f, 0.f};

#pragma unroll
            for (int kk = 0; kk < 8; ++kk) {
                const long bfr = *(const long*)(lbase + dsoff[kk] + p * 4096);
#pragma unroll
                for (int mi = 0; mi < 4; ++mi)
                    acc[mi] = __builtin_amdgcn_mfma_f32_16x16x32_fp8_fp8(
                        afrag[kk][mi], bfr, acc[mi], 0, 0, 0);
            }

            // streaming argmax update (diag guarded; strict '>' + ascending s)
            const int sv = S0 + sW + p * 16 + lrow;
#pragma unroll
            for (int mi = 0; mi < 4; ++mi) {
                const int tbase = rowBase + mi * 16 + lk * 4;
#pragma unroll
                for (int j = 0; j < 4; ++j) {
                    const float v = acc[mi][j];
                    const bool ok = (sv != tbase + j) && (v > best[mi][j]);
                    best[mi][j] = ok ? v : best[mi][j];
                    bidxv[mi][j] = ok ? sv : bidxv[mi][j];
                }
            }
        }

        asm volatile("s_waitcnt vmcnt(0)");
        __syncthreads();
    }

    // ---- reduce across the 16 lanes sharing each C-row, then global atomicMax ----
#pragma unroll
    for (int mi = 0; mi < 4; ++mi) {
#pragma unroll
        for (int j = 0; j < 4; ++j) {
            float v = best[mi][j];
            int   ix = bidxv[mi][j];
#pragma unroll
            for (int m = 8; m >= 1; m >>= 1) {
                float ov = __shfl_xor(v, m, 64);
                int   oi = __shfl_xor(ix, m, 64);
                if (ov > v || (ov == v && oi < ix)) { v = ov; ix = oi; }
            }
            if (lrow == 0) {
                const int row = rowBase + mi * 16 + lk * 4 + j;
                atomicMax(keys + batch * Tq + row, packkey(v, ix));
            }
        }
    }
}

// ---------------- Phase 3: exact fp32 distance + loss ----------------
__global__ void loss_kernel(const float* __restrict__ x, const u64* __restrict__ keys,
                            float* __restrict__ out) {
    const int lane = threadIdx.x & 63;
    const int wave = threadIdx.x >> 6;          // 4 waves / block
    const int gw = blockIdx.x * 4 + wave;       // 2048 global waves
    float lsum = 0.f;

    for (int row = gw; row < Bq * Tq; row += 2048) {
        const int b = row >> 12;
        const int t = row & (Tq - 1);
        const int s = (int)((u32)(~keys[row]));
        const float4* xt = (const float4*)(x + ((size_t)b * Tq + t) * Dq);
        const float4* xs = (const float4*)(x + ((size_t)b * Tq + s) * Dq);
        float4 a = xt[lane];
        float4 c = xs[lane];
        float dx = a.x - c.x + 1e-8f;
        float dy = a.y - c.y + 1e-8f;
        float dz = a.z - c.z + 1e-8f;
        float dw = a.w - c.w + 1e-8f;
        float sum = dx * dx + dy * dy + dz * dz + dw * dw;
#pragma unroll
        for (int m = 32; m >= 1; m >>= 1)
            sum += __shfl_xor(sum, m, 64);
        if (lane == 0)
            lsum += logf(sqrtf(sum) + 1e-8f);
    }

    __shared__ float red[4];
    if (lane == 0) red[wave] = lsum;
    __syncthreads();
    if (threadIdx.x == 0) {
        float s = red[0] + red[1] + red[2] + red[3];
        atomicAdd(out, -s * (1.0f / (Bq * Tq)));
    }
}

extern "C" void kernel_launch(void* const* d_in, const int* in_sizes, int n_in,
                              void* d_out, int out_size, void* d_ws, size_t ws_size,
                              hipStream_t stream) {
    const float* x = (const float*)d_in[0];
    float* out = (float*)d_out;

    unsigned char* xq = (unsigned char*)d_ws;                          // 8 MB fp8 copy
    u64* keys = (u64*)((char*)d_ws + (size_t)Bq * Tq * Dq);            // 256 KB keys

    hipMemsetAsync(d_out, 0, sizeof(float), stream);
    hipMemsetAsync(keys, 0, (size_t)Bq * Tq * sizeof(u64), stream);    // key=0 < any real

    const int n8 = Bq * Tq * Dq / 8;                                   // 1M threads
    cvt_kernel<<<n8 / 256, 256, 0, stream>>>(x, (uint2*)xq);
    argmax_kernel<<<512, 512, 0, stream>>>(xq, keys);
    loss_kernel<<<512, 256, 0, stream>>>(x, keys, out);
}

// Round 13
// 93.752 us; speedup vs baseline: 1.5216x; 1.5216x over previous
//
#include <hip/hip_runtime.h>
#include <math.h>

// KoLeo loss: B=8, T=4096, D=256 fp32 input.
// Phase 1: convert x -> fp8 e4m3 (HW v_cvt_pk_fp8_f32) in ws; also zero keys/out.
// Phase 2: per-batch Gram X·X^T via fp8 MFMA (R12 verified: fp8 argmax indices
//          IDENTICAL to fp32 -- absmax 0.0). R3-best structure: 256 blocks,
//          A register-resident, B staged via global_load_lds (swizzled dbuf);
//          fp8 halves staging + LDS-read bytes vs bf16 at equal occupancy.
// Phase 3: exact fp32 distances to argmax neighbor, loss = -mean(log(dist+eps)).

#define Bq 8
#define Tq 4096
#define Dq 256
#define SBLK 64              // s-columns staged per tile
#define NST 32               // tiles per s-half: 2048 / 64
#define S_HALF 2048
#define TILEB (SBLK * 256)   // 16 KB (fp8: 256 B per row)

typedef __attribute__((ext_vector_type(4))) float f32x4;
typedef unsigned int u32;
typedef unsigned long long u64;

__device__ __forceinline__ void gload_lds16(const void* g, void* l) {
    typedef __attribute__((address_space(1))) const unsigned int gu32;
    typedef __attribute__((address_space(3))) unsigned int lu32;
    __builtin_amdgcn_global_load_lds((gu32*)g, (lu32*)l, 16, 0, 0);
}

__device__ __forceinline__ u64 packkey(float v, int ix) {
    const u32 u = __float_as_uint(v);
    const u32 o = (u & 0x80000000u) ? ~u : (u | 0x80000000u);   // orderable fp32
    return ((u64)o << 32) | (u32)(~ix);                         // ties: low idx wins
}

// ---------------- Phase 1: fp32 -> fp8 e4m3 + zero keys/out ----------------
__global__ void cvt_kernel(const float* __restrict__ x, uint2* __restrict__ xq,
                           u64* __restrict__ keys, float* __restrict__ out) {
    const int i = blockIdx.x * blockDim.x + threadIdx.x;   // 0 .. 1M-1
    const float4* in = (const float4*)x;
    float4 v0 = in[2 * i], v1 = in[2 * i + 1];
    u32 a = 0, b = 0, c = 0, d = 0;
    asm volatile("v_cvt_pk_fp8_f32 %0, %1, %2" : "+v"(a) : "v"(v0.x), "v"(v0.y));
    asm volatile("v_cvt_pk_fp8_f32 %0, %1, %2" : "+v"(b) : "v"(v0.z), "v"(v0.w));
    asm volatile("v_cvt_pk_fp8_f32 %0, %1, %2" : "+v"(c) : "v"(v1.x), "v"(v1.y));
    asm volatile("v_cvt_pk_fp8_f32 %0, %1, %2" : "+v"(d) : "v"(v1.z), "v"(v1.w));
    uint2 o;
    o.x = (a & 0xffffu) | (b << 16);
    o.y = (c & 0xffffu) | (d << 16);
    xq[i] = o;
    if (i < Bq * Tq) keys[i] = 0;          // key=0 < any real packed key
    if (i == 0) *out = 0.f;                // loss accumulates via atomicAdd
}

// ---------------- Phase 2: fp8 Gram + streaming argmax ----------------
// Grid: 256 blocks = 8 batches x 16 row-tiles(256 rows) x 2 s-halves(2048 cols).
//   batch = bid & 7 -> same-batch blocks share an XCD L2 (fp8 panel = 1 MB).
// Block: 512 threads = 8 waves as 4M x 2N. Wave: 64 rows (mi=4) x 32 cols
//   (two 16-col passes, acc[4] reused -> 16 VGPR).
// REGISTER BUDGET IS THE CLIFF (R4/R12 evidence): footprint ~130 VGPR.
//   launch_bounds MUST be (512,2) (cap 256 -> clean alloc, 2 waves/SIMD).
//   (512,4) caps at 128 -> allocator spills afrag to scratch: VGPR_Count drops
//   to 64, WRITE_SIZE explodes to 67 MB, 1.6x slower (measured R12).
// mfma_f32_16x16x32_fp8_fp8 layout verified by R12 (indices == fp32 argmax).
// LDS: 2 x 16 KB dbuf; swizzle XOR ((s&15)<<4) on 256 B rows (16B-granular ->
//   staging-compatible; b64 reads ~2-way bank aliasing = free).
__global__ __launch_bounds__(512, 2)
void argmax_kernel(const unsigned char* __restrict__ xq, u64* __restrict__ keys) {
    const int bid   = blockIdx.x;
    const int batch = bid & 7;
    const int rt    = (bid >> 3) & 15;     // row-tile 0..15 (256 rows each)
    const int sh    = bid >> 7;            // s-half 0..1
    const int tid   = threadIdx.x;
    const int lane  = tid & 63;
    const int wave  = tid >> 6;            // 0..7
    const int waveM = wave >> 1;           // 0..3
    const int waveN = wave & 1;            // 0..1
    const int lrow  = lane & 15;           // A-row / B-col / C-col
    const int lk    = lane >> 4;           // k-group / C row-group

    const unsigned char* xB = xq + (size_t)batch * Tq * Dq;   // fp8, row = 256 B
    const int rowBase = rt * 256 + waveM * 64;                // wave's 64 rows
    const int sHalfBase = sh * S_HALF;
    const int sW = waveN * 32;                                // wave's 32-col slice

    __shared__ char smem[2 * TILEB];                          // 32 KB double buffer

    // ---- A fragments: afrag[kk][mi] = 32 x i64 = 64 VGPR ----
    long afrag[8][4];
#pragma unroll
    for (int mi = 0; mi < 4; ++mi) {
        const unsigned char* rp = xB + (size_t)(rowBase + mi * 16 + lrow) * Dq + lk * 8;
#pragma unroll
        for (int kk = 0; kk < 8; ++kk)
            afrag[kk][mi] = *(const long*)(rp + kk * 32);
    }

    // ---- staging source offsets (2 x 16B per thread per 16 KB tile) ----
    // LDS linear slot ls holds global byte (q ^ ((s&15)<<4)) of row s=ls>>8
    // (linear dest + inverse-swizzled source, rule #21).
    int g_off[2];
#pragma unroll
    for (int it = 0; it < 2; ++it) {
        const int ls = it * 8192 + tid * 16;
        const int s_local = ls >> 8;
        const int q = ls & 255;
        g_off[it] = s_local * 256 + (q ^ ((s_local & 15) << 4));
    }
    // ---- ds-read offsets (pass 0); pass 1 = +16 rows = +4096 (swizzle
    //      invariant: (s+16)&15 == s&15) ----
    int dsoff[8];
    {
        const int s_local = sW + lrow;
#pragma unroll
        for (int kk = 0; kk < 8; ++kk)
            dsoff[kk] = s_local * 256 + ((kk * 32 + lk * 8) ^ ((s_local & 15) << 4));
    }

    auto STAGE = [&](int st, int buf) {
        const unsigned char* gsrc = xB + (size_t)(sHalfBase + st * SBLK) * 256;
        char* lbase = smem + buf * TILEB;
#pragma unroll
        for (int it = 0; it < 2; ++it)
            gload_lds16(gsrc + g_off[it], lbase + it * 8192 + tid * 16);
    };

    float best[4][4];   // [mi][j]
    int   bidxv[4][4];
#pragma unroll
    for (int mi = 0; mi < 4; ++mi)
#pragma unroll
        for (int j = 0; j < 4; ++j) { best[mi][j] = -1e30f; bidxv[mi][j] = 0; }

    STAGE(0, 0);
    asm volatile("s_waitcnt vmcnt(0)");
    __syncthreads();

    for (int st = 0; st < NST; ++st) {
        const int buf = st & 1;
        if (st + 1 < NST) STAGE(st + 1, buf ^ 1);

        const char* lbase = smem + buf * TILEB;
        const int S0 = sHalfBase + st * SBLK;

#pragma unroll
        for (int p = 0; p < 2; ++p) {          // two 16-col passes per wave
            f32x4 acc[4];
#pragma unroll
            for (int mi = 0; mi < 4; ++mi)
                acc[mi] = (f32x4){0.f, 0.f, 0.f, 0.f};

#pragma unroll
            for (int kk = 0; kk < 8; ++kk) {
                const long bfr = *(const long*)(lbase + dsoff[kk] + p * 4096);
#pragma unroll
                for (int mi = 0; mi < 4; ++mi)
                    acc[mi] = __builtin_amdgcn_mfma_f32_16x16x32_fp8_fp8(
                        afrag[kk][mi], bfr, acc[mi], 0, 0, 0);
            }

            // streaming argmax; diag check hoisted to a wave-uniform branch
            // (only the pass whose 16 cols intersect the wave's 64 rows)
            const int colB = S0 + sW + p * 16;
            const int sv = colB + lrow;
            if (colB < rowBase + 64 && rowBase < colB + 16) {
#pragma unroll
                for (int mi = 0; mi < 4; ++mi) {
                    const int tbase = rowBase + mi * 16 + lk * 4;
#pragma unroll
                    for (int j = 0; j < 4; ++j) {
                        const float v = acc[mi][j];
                        const bool ok = (sv != tbase + j) && (v > best[mi][j]);
                        best[mi][j] = ok ? v : best[mi][j];
                        bidxv[mi][j] = ok ? sv : bidxv[mi][j];
                    }
                }
            } else {
#pragma unroll
                for (int mi = 0; mi < 4; ++mi) {
#pragma unroll
                    for (int j = 0; j < 4; ++j) {
                        const float v = acc[mi][j];
                        const bool ok = (v > best[mi][j]);
                        best[mi][j] = ok ? v : best[mi][j];
                        bidxv[mi][j] = ok ? sv : bidxv[mi][j];
                    }
                }
            }
        }

        asm volatile("s_waitcnt vmcnt(0)");
        __syncthreads();
    }

    // ---- reduce across the 16 lanes sharing each C-row, then global atomicMax ----
#pragma unroll
    for (int mi = 0; mi < 4; ++mi) {
#pragma unroll
        for (int j = 0; j < 4; ++j) {
            float v = best[mi][j];
            int   ix = bidxv[mi][j];
#pragma unroll
            for (int m = 8; m >= 1; m >>= 1) {
                float ov = __shfl_xor(v, m, 64);
                int   oi = __shfl_xor(ix, m, 64);
                if (ov > v || (ov == v && oi < ix)) { v = ov; ix = oi; }
            }
            if (lrow == 0) {
                const int row = rowBase + mi * 16 + lk * 4 + j;
                atomicMax(keys + batch * Tq + row, packkey(v, ix));
            }
        }
    }
}

// ---------------- Phase 3: exact fp32 distance + loss ----------------
__global__ void loss_kernel(const float* __restrict__ x, const u64* __restrict__ keys,
                            float* __restrict__ out) {
    const int lane = threadIdx.x & 63;
    const int wave = threadIdx.x >> 6;          // 4 waves / block
    const int gw = blockIdx.x * 4 + wave;       // 2048 global waves
    float lsum = 0.f;

    for (int row = gw; row < Bq * Tq; row += 2048) {
        const int b = row >> 12;
        const int t = row & (Tq - 1);
        const int s = (int)((u32)(~keys[row]));
        const float4* xt = (const float4*)(x + ((size_t)b * Tq + t) * Dq);
        const float4* xs = (const float4*)(x + ((size_t)b * Tq + s) * Dq);
        float4 a = xt[lane];
        float4 c = xs[lane];
        float dx = a.x - c.x + 1e-8f;
        float dy = a.y - c.y + 1e-8f;
        float dz = a.z - c.z + 1e-8f;
        float dw = a.w - c.w + 1e-8f;
        float sum = dx * dx + dy * dy + dz * dz + dw * dw;
#pragma unroll
        for (int m = 32; m >= 1; m >>= 1)
            sum += __shfl_xor(sum, m, 64);
        if (lane == 0)
            lsum += logf(sqrtf(sum) + 1e-8f);
    }

    __shared__ float red[4];
    if (lane == 0) red[wave] = lsum;
    __syncthreads();
    if (threadIdx.x == 0) {
        float s = red[0] + red[1] + red[2] + red[3];
        atomicAdd(out, -s * (1.0f / (Bq * Tq)));
    }
}

extern "C" void kernel_launch(void* const* d_in, const int* in_sizes, int n_in,
                              void* d_out, int out_size, void* d_ws, size_t ws_size,
                              hipStream_t stream) {
    const float* x = (const float*)d_in[0];
    float* out = (float*)d_out;

    unsigned char* xq = (unsigned char*)d_ws;                          // 8 MB fp8 copy
    u64* keys = (u64*)((char*)d_ws + (size_t)Bq * Tq * Dq);            // 256 KB keys

    const int n8 = Bq * Tq * Dq / 8;                                   // 1M threads
    cvt_kernel<<<n8 / 256, 256, 0, stream>>>(x, (uint2*)xq, keys, out);
    argmax_kernel<<<256, 512, 0, stream>>>(xq, keys);
    loss_kernel<<<512, 256, 0, stream>>>(x, keys, out);
}